// Round 12
// baseline (332.113 us; speedup 1.0000x reference)
//
#include <hip/hip_runtime.h>
#include <hip/hip_bf16.h>

typedef __hip_bfloat16 bf16;
typedef short bf16x8 __attribute__((ext_vector_type(8)));
typedef float f32x4 __attribute__((ext_vector_type(4)));

#define CC 16
#define PP 256
#define DMH 512
#define DIH 1024
#define MM (CC*PP)   /* 4096 rows (c,p) */
#define NST 16
#define NDT 32
#define LOG2E 1.44269504088896f

__device__ __forceinline__ float b2f(bf16 v){ return __bfloat162float(v); }
__device__ __forceinline__ bf16  f2b(float v){ return __float2bfloat16(v); }

__device__ __forceinline__ float geluf(float x){
  float x3 = x*x*x;
  return 0.5f*x*(1.0f + tanhf(0.7978845608028654f*x + 0.035677408136300125f*x3));
}
__device__ __forceinline__ float softplusf(float x){
  if (x > 20.0f) return x;
  return log1pf(expf(x));
}

__device__ __forceinline__ void g2l16(const bf16* g, bf16* l){
  __builtin_amdgcn_global_load_lds(
      (const __attribute__((address_space(1))) void*)g,
      (__attribute__((address_space(3))) void*)(uint32_t)(uintptr_t)l,
      16, 0, 0);
}

// sum over the 16 lanes of a DPP row; result valid at lane (row_base+15)
__device__ __forceinline__ float row_sum16(float y){
  int t;
  t = __builtin_amdgcn_update_dpp(0, __float_as_int(y), 0x111, 0xf, 0xf, true); // row_shr:1
  y += __int_as_float(t);
  t = __builtin_amdgcn_update_dpp(0, __float_as_int(y), 0x112, 0xf, 0xf, true); // row_shr:2
  y += __int_as_float(t);
  t = __builtin_amdgcn_update_dpp(0, __float_as_int(y), 0x114, 0xf, 0xf, true); // row_shr:4
  y += __int_as_float(t);
  t = __builtin_amdgcn_update_dpp(0, __float_as_int(y), 0x118, 0xf, 0xf, true); // row_shr:8
  y += __int_as_float(t);
  return y;
}

// ---------------- fused prep: casts + conv repack + LDS-tiled transpose + xdb zero ----
// ranges: [0,3136) casts | [3136,7232) cwT | [7232,7360) in_w transpose | [7360,7616) zero
__global__ void prep_all(const float* __restrict__ x, const float* __restrict__ in_w,
                         const float* __restrict__ out_w, const float* __restrict__ param_w,
                         const float* __restrict__ conv_w,
                         bf16* __restrict__ xbf, bf16* __restrict__ inwz,
                         bf16* __restrict__ outwb, bf16* __restrict__ pwb,
                         bf16* __restrict__ cwT, bf16* __restrict__ inwT,
                         float4* __restrict__ xdb4)
{
  const int b = blockIdx.x, tid = threadIdx.x;
  if (b < 3136){
    const float* src; bf16* dst; int i;
    if (b < 2048)      { src = x;                       dst = xbf;   i = b*256 + tid; }
    else if (b < 2560) { src = in_w + (size_t)DIH*DMH;  dst = inwz;  i = (b-2048)*256 + tid; }
    else if (b < 3072) { src = out_w;                   dst = outwb; i = (b-2560)*256 + tid; }
    else               { src = param_w;                 dst = pwb;   i = (b-3072)*256 + tid; }
    float4 v = ((const float4*)src)[i];
    bf16 o[4] = {f2b(v.x), f2b(v.y), f2b(v.z), f2b(v.w)};
    *(ushort4*)&dst[(size_t)i*4] = *(const ushort4*)o;
  } else if (b < 7232){
    const size_t idx = (size_t)(b-3136)*256 + tid;      // o*1024 + i
    const float4 v = *(const float4*)(conv_w + idx*4);  // [o][i][tap] -> [tap][o][i]
    cwT[idx]                     = f2b(v.x);
    cwT[(size_t)DIH*DIH   + idx] = f2b(v.y);
    cwT[(size_t)2*DIH*DIH + idx] = f2b(v.z);
    cwT[(size_t)3*DIH*DIH + idx] = f2b(v.w);
  } else if (b < 7360){
    // in_w xi-half [i<1024][m<512] -> inwT [m][i], 64x64 LDS tile
    __shared__ float T[64][65];
    const int b2 = b - 7232;
    const int i0 = (b2 >> 3)*64, m0 = (b2 & 7)*64;
    const int r = tid >> 2, c0 = (tid & 3)*16;
    #pragma unroll
    for (int t = 0; t < 4; t++){
      float4 v = *(const float4*)&in_w[(size_t)(i0 + r)*DMH + m0 + c0 + t*4];
      T[r][c0+t*4+0] = v.x; T[r][c0+t*4+1] = v.y;
      T[r][c0+t*4+2] = v.z; T[r][c0+t*4+3] = v.w;
    }
    __syncthreads();
    bf16 o[16];
    #pragma unroll
    for (int t = 0; t < 16; t++) o[t] = f2b(T[c0 + t][r]);
    *(ushort4*)&inwT[(size_t)(m0 + r)*DIH + i0 + c0]      = *(const ushort4*)&o[0];
    *(ushort4*)&inwT[(size_t)(m0 + r)*DIH + i0 + c0 + 4]  = *(const ushort4*)&o[4];
    *(ushort4*)&inwT[(size_t)(m0 + r)*DIH + i0 + c0 + 8]  = *(const ushort4*)&o[8];
    *(ushort4*)&inwT[(size_t)(m0 + r)*DIH + i0 + c0 + 12] = *(const ushort4*)&o[12];
  } else {
    xdb4[(b-7360)*256 + tid] = make_float4(0.f,0.f,0.f,0.f);
  }
}

// cb2[o] = conv_b[o] + sum_i (sum_k conv_w[o,i,k]) * in_b[i]
__global__ void fold_bias(const float* __restrict__ cw, const float* __restrict__ in_b,
                          const float* __restrict__ conv_b, float* __restrict__ cb2){
  const int o = blockIdx.x;
  const int tid = threadIdx.x;
  float acc = 0.0f;
  #pragma unroll
  for (int t = 0; t < 4; t++){
    int i = tid + t*256;
    const float4 w = *(const float4*)(cw + (size_t)o*4096 + (size_t)i*4);
    acc += (w.x + w.y + w.z + w.w) * in_b[i];
  }
  for (int off = 32; off; off >>= 1) acc += __shfl_down(acc, off);
  __shared__ float ls[4];
  if ((tid & 63) == 0) ls[tid >> 6] = acc;
  __syncthreads();
  if (tid == 0) cb2[o] = conv_b[o] + ls[0] + ls[1] + ls[2] + ls[3];
}

// ---------------- MFMA GEMM: C[m,n] = epi( sum_k A[m,k]*B[n,k] + bias[n] ) -------------
#define TBK 64

template<int EPI, int CONV, int NFRAG>
__launch_bounds__(256)
__global__ void mfma_gemm(const bf16* __restrict__ A, int lda,
                          const bf16* __restrict__ B, int ldb,
                          const float* __restrict__ bias,
                          float* __restrict__ outF,
                          bf16* __restrict__ outB0,
                          int ldo, int K, int azs, int ozs, int kzs)
{
  __shared__ bf16 As[128*TBK];           // 16 KB
  __shared__ bf16 Bs[32*NFRAG*TBK];      // 4/8 KB
  const int tid  = threadIdx.x;
  const int lane = tid & 63;
  const int wave = tid >> 6;
  const int wr = (wave >> 1) * 64;
  const int wc = (wave & 1) * 16 * NFRAG;
  const int mBase = blockIdx.x * 128;
  const int nBase = blockIdx.y * (32*NFRAG);
  A += (size_t)blockIdx.z * azs;
  const int nOff = blockIdx.z * ozs;
  const int koff = blockIdx.z * kzs;

  f32x4 acc[4][NFRAG] = {};

  for (int k0 = 0; k0 < K; k0 += TBK) {
    __syncthreads();
    #pragma unroll
    for (int it = 0; it < 4; it++) {      // As: 1024 chunks of 16B
      const int idx = it*256 + tid;
      const int r = idx >> 3, c16 = idx & 7;
      const bf16* ga;
      if (CONV) {
        const int tap = k0 >> 9, kk = k0 & 511;
        const int m = mBase + r;
        const int cc = m >> 8;
        int p = (m & 255) + tap - 2;
        p = min(max(p, 0), PP-1);
        ga = A + ((size_t)(cc*PP + p))*DMH + kk + c16*8;
      } else {
        ga = A + (size_t)(mBase + r)*lda + koff + k0 + c16*8;
      }
      g2l16(ga, &As[(size_t)idx*8]);
    }
    #pragma unroll
    for (int it = 0; it < NFRAG; it++) {  // Bs: 256*NFRAG chunks of 16B
      const int idx = it*256 + tid;
      const int r = idx >> 3, c16 = idx & 7;
      const bf16* gb = B + (size_t)(nBase + r)*ldb + koff + k0 + c16*8;
      g2l16(gb, &Bs[(size_t)idx*8]);
    }
    __syncthreads();
    #pragma unroll
    for (int ks = 0; ks < 2; ks++) {
      bf16x8 af[4], bfr[NFRAG];
      #pragma unroll
      for (int r = 0; r < 4; r++)
        af[r] = *(const bf16x8*)&As[(wr + r*16 + (lane & 15))*TBK + ks*32 + (lane>>4)*8];
      #pragma unroll
      for (int c = 0; c < NFRAG; c++)
        bfr[c] = *(const bf16x8*)&Bs[(wc + c*16 + (lane & 15))*TBK + ks*32 + (lane>>4)*8];
      #pragma unroll
      for (int r = 0; r < 4; r++)
        #pragma unroll
        for (int c = 0; c < NFRAG; c++)
          acc[r][c] = __builtin_amdgcn_mfma_f32_16x16x32_bf16(af[r], bfr[c], acc[r][c], 0, 0, 0);
    }
  }

  const int col0 = lane & 15;
  const int row0 = (lane >> 4) * 4;
  #pragma unroll
  for (int r = 0; r < 4; r++) {
    #pragma unroll
    for (int c = 0; c < NFRAG; c++) {
      #pragma unroll
      for (int reg = 0; reg < 4; reg++) {
        const int m = mBase + wr + r*16 + row0 + reg;
        const int n = nBase + wc + c*16 + col0;
        const float av = acc[r][c][reg];
        if (EPI == 0) {
          outF[(size_t)m*ldo + n] = av + bias[n];
        } else if (EPI == 1) {
          outB0[(size_t)m*ldo + n] = f2b(geluf(av + bias[n]));
        } else if (EPI == 2) {
          outB0[(size_t)m*ldo + n] = f2b(geluf(geluf(av + bias[n])));
        } else if (EPI == 3) {
          outB0[(size_t)m*ldo + n + nOff] = f2b(av);
        } else {
          const float vv = av + ((blockIdx.z == 0) ? bias[n] : 0.0f);
          atomicAdd(&outF[(size_t)m*ldo + n], vv);
        }
      }
    }
  }
}

// ---------------- chunked selective scan ----------------
// scan_a: dt GEMM tile (stored to dtg plane + LDS), 16-step chunk from s=0,
//         Ap = exp2(a2*sum dt). scan_c: stages dtg (no recompute), in-block
//         prefix over AS (scan_b fused), replay, y/gz/D applied in writer phase.
__launch_bounds__(256)
__global__ void scan_a(const float* __restrict__ xdb, const bf16* __restrict__ xi,
                       const float* __restrict__ dt_w, const float* __restrict__ dt_b,
                       const float* __restrict__ A_log, float2* __restrict__ AS,
                       float* __restrict__ dtg)
{
  const int g = blockIdx.x, dg = blockIdx.y, c = blockIdx.z;
  const int tid = threadIdx.x;
  const int n = tid & 15, dl = tid >> 4;
  const int d0 = dg*16;
  const int d = d0 + dl;
  const int m0 = c*PP + g*16;
  __shared__ float  xdbT[16][68];   // +4 pad
  __shared__ float  dtw[16][33];    // +1 pad
  __shared__ float2 pxT[16][16];    // {dt, xi}
  {
    const int r = tid >> 4, c4 = (tid & 15)*4;
    *(float4*)&xdbT[r][c4] = *(const float4*)&xdb[(size_t)(m0 + r)*64 + c4];
    if (tid < 128){
      const int rr = tid >> 3, cc = (tid & 7)*4;
      *(float4*)&dtw[rr][cc] = *(const float4*)&dt_w[(size_t)(d0 + rr)*NDT + cc];
    }
    ushort u = ((const ushort*)xi)[(size_t)(m0 + r)*DIH + d0 + (tid & 15)];
    bf16 h; *(ushort*)&h = u;
    pxT[r][tid & 15].y = b2f(h);
  }
  const float a2 = -__expf(A_log[(size_t)d*NST + n]) * LOG2E;
  __syncthreads();
  {
    const int j = tid >> 4, dl2 = tid & 15;
    float acc = dt_b[d0 + dl2];
    #pragma unroll
    for (int k = 0; k < 32; k++) acc += xdbT[j][k] * dtw[dl2][k];
    acc = softplusf(acc);
    pxT[j][dl2].x = acc;
    dtg[(size_t)(m0 + j)*DIH + d0 + dl2] = acc;
  }
  __syncthreads();
  float Bv[16];
  #pragma unroll
  for (int j = 0; j < 16; j++) Bv[j] = xdbT[j][32 + n];
  float s = 0.f, dtsum = 0.f;
  #pragma unroll
  for (int j = 0; j < 16; j++){
    const float2 px = pxT[j][dl];
    const float e = exp2f(px.x * a2);
    s = s*e + (px.x * px.y) * Bv[j];
    dtsum += px.x;
  }
  float2 o; o.x = exp2f(dtsum * a2); o.y = s;
  AS[(((size_t)(c*64+dg))*16 + g)*256 + tid] = o;
}

__launch_bounds__(256)
__global__ void scan_c(const float* __restrict__ xdb, const bf16* __restrict__ xi,
                       const bf16* __restrict__ gz, const float* __restrict__ dtg,
                       const float* __restrict__ A_log, const float* __restrict__ Dp,
                       const float* __restrict__ s0, const float2* __restrict__ AS,
                       bf16* __restrict__ ypre, float* __restrict__ state_out)
{
  const int g = blockIdx.x, dg = blockIdx.y, c = blockIdx.z;
  const int tid = threadIdx.x;
  const int n = tid & 15, dl = tid >> 4;
  const int d0 = dg*16;
  const int d = d0 + dl;
  const int m0 = c*PP + g*16;
  __shared__ float  bcT[16][34];    // B|C cols 32..63, +2 pad
  __shared__ float2 pxT[16][16];    // {dt, xi}
  __shared__ ushort gzT[16][16];
  __shared__ float  ybF[16][16];
  __shared__ float  DvT[16];
  {
    const int r = tid >> 4, cc = (tid & 15)*2;
    *(float2*)&bcT[r][cc] = *(const float2*)&xdb[(size_t)(m0 + r)*64 + 32 + cc];
    const int dd = tid & 15;
    float2 px;
    px.x = dtg[(size_t)(m0 + r)*DIH + d0 + dd];
    ushort u = ((const ushort*)xi)[(size_t)(m0 + r)*DIH + d0 + dd];
    bf16 h; *(ushort*)&h = u;
    px.y = b2f(h);
    pxT[r][dd] = px;
    gzT[r][dd] = ((const ushort*)gz)[(size_t)(m0 + r)*DIH + d0 + dd];
    if (tid < 16) DvT[tid] = Dp[d0 + tid];
  }
  const float a2 = -__expf(A_log[(size_t)d*NST + n]) * LOG2E;
  // fused scan_b: in-block prefix over AS
  float s = s0[((size_t)c*DIH + d)*NST + n];
  {
    const size_t base = (((size_t)(c*64+dg))*16)*256 + tid;
    for (int gp = 0; gp < g; gp++){
      const float2 f = AS[base + (size_t)gp*256];
      s = f.y + f.x*s;
    }
  }
  __syncthreads();
  float Bv[16], Cv[16];
  #pragma unroll
  for (int j = 0; j < 16; j++){ Bv[j] = bcT[j][n]; Cv[j] = bcT[j][16 + n]; }
  #pragma unroll
  for (int j = 0; j < 16; j++){
    const float2 px = pxT[j][dl];
    const float e = exp2f(px.x * a2);
    s = s*e + (px.x * px.y) * Bv[j];
    const float y = row_sum16(s * Cv[j]);   // valid at n==15
    if (n == 15) ybF[j][dl] = y;
  }
  __syncthreads();
  if (tid < 32){
    const int j = tid >> 1, half = (tid & 1)*8;
    ushort o[8];
    #pragma unroll
    for (int t = 0; t < 8; t++){
      const int dd = half + t;
      bf16 gh; *(ushort*)&gh = gzT[j][dd];
      bf16 h = f2b((ybF[j][dd] + DvT[dd]*pxT[j][dd].y) * b2f(gh));
      o[t] = *(const ushort*)&h;
    }
    *(uint4*)((ushort*)ypre + (size_t)(m0 + j)*DIH + d0 + half) = *(const uint4*)o;
  }
  if (g == 15) state_out[((size_t)c*DIH + d)*NST + n] = s;
}

extern "C" void kernel_launch(void* const* d_in, const int* in_sizes, int n_in,
                              void* d_out, int out_size, void* d_ws, size_t ws_size,
                              hipStream_t stream) {
  const float* x       = (const float*)d_in[0];
  const float* s0      = (const float*)d_in[1];
  const float* in_w    = (const float*)d_in[2];
  const float* in_b    = (const float*)d_in[3];
  const float* conv_w  = (const float*)d_in[4];
  const float* conv_b  = (const float*)d_in[5];
  const float* param_w = (const float*)d_in[6];
  const float* param_b = (const float*)d_in[7];
  const float* dt_w    = (const float*)d_in[8];
  const float* dt_b    = (const float*)d_in[9];
  const float* out_w   = (const float*)d_in[10];
  const float* out_b   = (const float*)d_in[11];
  const float* A_log   = (const float*)d_in[12];
  const float* Dp      = (const float*)d_in[13];

  char* ws = (char*)d_ws;
  bf16*   xi    = (bf16*)ws;   ws += (size_t)MM*DIH*2;     //  8 MB
  bf16*   gz    = (bf16*)ws;   ws += (size_t)MM*DIH*2;     //  8 MB
  float*  xdb   = (float*)ws;  ws += (size_t)MM*64*4;      //  1 MB
  float*  cb2   = (float*)ws;  ws += 4096;                 //  4 KB
  bf16*   ypre  = (bf16*)ws;   ws += (size_t)MM*DIH*2;     //  8 MB
  bf16*   outwb = (bf16*)ws;   ws += (size_t)DMH*DIH*2;    //  1 MB
  bf16*   pwb   = (bf16*)ws;   ws += (size_t)64*DIH*2;     // 128 KB
  float*  dtg   = (float*)ws;  ws += (size_t)MM*DIH*4;     // 16 MB (scan_a -> scan_c)
  char*   U     = ws;          ws += (size_t)32*1024*1024; // union region, 32 MB
  // early-phase tenants of U (all dead before scan_a):
  bf16* Wfb  = (bf16*)(U);
  bf16* xbf  = (bf16*)(U + (size_t) 4*1024*1024);
  bf16* inwz = (bf16*)(U + (size_t) 8*1024*1024);
  bf16* inwT = (bf16*)(U + (size_t) 9*1024*1024);
  bf16* cwT  = (bf16*)(U + (size_t)10*1024*1024);
  // scan-phase tenant of U:
  float2* AS  = (float2*)(U);                              // 32 MB

  float* y_out  = (float*)d_out;                           // [C,P,DM] fp32
  float* st_out = y_out + (size_t)MM*DMH;                  // [C,DI,16] fp32

  // fused prep (casts, conv repack, tiled transpose, xdb zero) + fold_bias
  prep_all<<<7616, 256, 0, stream>>>(x, in_w, out_w, param_w, conv_w,
                                     xbf, inwz, outwb, pwb, cwT, inwT, (float4*)xdb);
  fold_bias<<<DIH, 256, 0, stream>>>(conv_w, in_b, conv_b, cb2);

  // fold: Wf[k][o][m] = sum_i conv_w[o,i,k]*in_w[i,m]   (4 taps via grid.z)
  mfma_gemm<3,0,2><<<dim3(DIH/128, DMH/64, 4), 256, 0, stream>>>(
      cwT, DIH, inwT, DIH, nullptr, nullptr, Wfb, 4*DMH, DIH, DIH*DIH, DMH, 0);
  // z-half in_proj: gelu(gelu(x @ in_w_z^T + b_z)) -> gz (contiguous bf16)
  mfma_gemm<2,0,2><<<dim3(MM/128, DIH/64), 256, 0, stream>>>(
      xbf, DMH, inwz, DMH, in_b + DIH, nullptr, gz, DIH, DMH, 0, 0, 0);
  // fused conv: gelu( sum_tap x[clamp] @ Wf_tap^T + cb2 ) -> xi (contiguous bf16)
  mfma_gemm<1,1,2><<<dim3(MM/128, DIH/64), 256, 0, stream>>>(
      xbf, DMH, Wfb, 4*DMH, cb2, nullptr, xi, DIH, 4*DMH, 0, 0, 0);
  // x_db = xi @ param_w.T + param_b   (MFMA split-K=8, fp32 atomics into zeroed xdb)
  mfma_gemm<4,0,2><<<dim3(MM/128, 1, 8), 256, 0, stream>>>(
      xi, DIH, pwb, DIH, param_b, xdb, nullptr, 64, 128, 0, 0, 128);
  // chunked scan: A (dt GEMM + chunk-from-0 + dtg store) -> C (prefix fused + replay)
  scan_a<<<dim3(16, 64, CC), 256, 0, stream>>>(xdb, xi, dt_w, dt_b, A_log, AS, dtg);
  scan_c<<<dim3(16, 64, CC), 256, 0, stream>>>(xdb, xi, gz, dtg, A_log, Dp, s0, AS,
                                               ypre, st_out);
  // out projection
  mfma_gemm<0,0,1><<<dim3(MM/128, DMH/32), 256, 0, stream>>>(
      ypre, DIH, outwb, DIH, out_b, y_out, nullptr, DMH, DIH, 0, 0, 0);
}

// Round 13
// 310.858 us; speedup vs baseline: 1.0684x; 1.0684x over previous
//
#include <hip/hip_runtime.h>
#include <hip/hip_bf16.h>

typedef __hip_bfloat16 bf16;
typedef short bf16x8 __attribute__((ext_vector_type(8)));
typedef float f32x4 __attribute__((ext_vector_type(4)));

#define CC 16
#define PP 256
#define DMH 512
#define DIH 1024
#define MM (CC*PP)   /* 4096 rows (c,p) */
#define NST 16
#define NDT 32
#define LOG2E 1.44269504088896f

__device__ __forceinline__ float b2f(bf16 v){ return __bfloat162float(v); }
__device__ __forceinline__ bf16  f2b(float v){ return __float2bfloat16(v); }

__device__ __forceinline__ float geluf(float x){
  float x3 = x*x*x;
  return 0.5f*x*(1.0f + tanhf(0.7978845608028654f*x + 0.035677408136300125f*x3));
}
__device__ __forceinline__ float softplusf(float x){
  if (x > 20.0f) return x;
  return log1pf(expf(x));
}

__device__ __forceinline__ void g2l16(const bf16* g, bf16* l){
  __builtin_amdgcn_global_load_lds(
      (const __attribute__((address_space(1))) void*)g,
      (__attribute__((address_space(3))) void*)(uint32_t)(uintptr_t)l,
      16, 0, 0);
}

// sum over the 16 lanes of a DPP row; result valid at lane (row_base+15)
__device__ __forceinline__ float row_sum16(float y){
  int t;
  t = __builtin_amdgcn_update_dpp(0, __float_as_int(y), 0x111, 0xf, 0xf, true); // row_shr:1
  y += __int_as_float(t);
  t = __builtin_amdgcn_update_dpp(0, __float_as_int(y), 0x112, 0xf, 0xf, true); // row_shr:2
  y += __int_as_float(t);
  t = __builtin_amdgcn_update_dpp(0, __float_as_int(y), 0x114, 0xf, 0xf, true); // row_shr:4
  y += __int_as_float(t);
  t = __builtin_amdgcn_update_dpp(0, __float_as_int(y), 0x118, 0xf, 0xf, true); // row_shr:8
  y += __int_as_float(t);
  return y;
}

// ---------------- fused prep: casts + conv repack + LDS-tiled transpose + xdb zero ----
__global__ void prep_all(const float* __restrict__ x, const float* __restrict__ in_w,
                         const float* __restrict__ out_w, const float* __restrict__ param_w,
                         const float* __restrict__ conv_w,
                         bf16* __restrict__ xbf, bf16* __restrict__ inwz,
                         bf16* __restrict__ outwb, bf16* __restrict__ pwb,
                         bf16* __restrict__ cwT, bf16* __restrict__ inwT,
                         float4* __restrict__ xdb4)
{
  const int b = blockIdx.x, tid = threadIdx.x;
  if (b < 3136){
    const float* src; bf16* dst; int i;
    if (b < 2048)      { src = x;                       dst = xbf;   i = b*256 + tid; }
    else if (b < 2560) { src = in_w + (size_t)DIH*DMH;  dst = inwz;  i = (b-2048)*256 + tid; }
    else if (b < 3072) { src = out_w;                   dst = outwb; i = (b-2560)*256 + tid; }
    else               { src = param_w;                 dst = pwb;   i = (b-3072)*256 + tid; }
    float4 v = ((const float4*)src)[i];
    bf16 o[4] = {f2b(v.x), f2b(v.y), f2b(v.z), f2b(v.w)};
    *(ushort4*)&dst[(size_t)i*4] = *(const ushort4*)o;
  } else if (b < 7232){
    const size_t idx = (size_t)(b-3136)*256 + tid;      // o*1024 + i
    const float4 v = *(const float4*)(conv_w + idx*4);  // [o][i][tap] -> [tap][o][i]
    cwT[idx]                     = f2b(v.x);
    cwT[(size_t)DIH*DIH   + idx] = f2b(v.y);
    cwT[(size_t)2*DIH*DIH + idx] = f2b(v.z);
    cwT[(size_t)3*DIH*DIH + idx] = f2b(v.w);
  } else if (b < 7360){
    // in_w xi-half [i<1024][m<512] -> inwT [m][i], 64x64 LDS tile
    __shared__ float T[64][65];
    const int b2 = b - 7232;
    const int i0 = (b2 >> 3)*64, m0 = (b2 & 7)*64;
    const int r = tid >> 2, c0 = (tid & 3)*16;
    #pragma unroll
    for (int t = 0; t < 4; t++){
      float4 v = *(const float4*)&in_w[(size_t)(i0 + r)*DMH + m0 + c0 + t*4];
      T[r][c0+t*4+0] = v.x; T[r][c0+t*4+1] = v.y;
      T[r][c0+t*4+2] = v.z; T[r][c0+t*4+3] = v.w;
    }
    __syncthreads();
    bf16 o[16];
    #pragma unroll
    for (int t = 0; t < 16; t++) o[t] = f2b(T[c0 + t][r]);
    *(ushort4*)&inwT[(size_t)(m0 + r)*DIH + i0 + c0]      = *(const ushort4*)&o[0];
    *(ushort4*)&inwT[(size_t)(m0 + r)*DIH + i0 + c0 + 4]  = *(const ushort4*)&o[4];
    *(ushort4*)&inwT[(size_t)(m0 + r)*DIH + i0 + c0 + 8]  = *(const ushort4*)&o[8];
    *(ushort4*)&inwT[(size_t)(m0 + r)*DIH + i0 + c0 + 12] = *(const ushort4*)&o[12];
  } else {
    xdb4[(b-7360)*256 + tid] = make_float4(0.f,0.f,0.f,0.f);
  }
}

// cb2[o] = conv_b[o] + sum_i (sum_k conv_w[o,i,k]) * in_b[i]
__global__ void fold_bias(const float* __restrict__ cw, const float* __restrict__ in_b,
                          const float* __restrict__ conv_b, float* __restrict__ cb2){
  const int o = blockIdx.x;
  const int tid = threadIdx.x;
  float acc = 0.0f;
  #pragma unroll
  for (int t = 0; t < 4; t++){
    int i = tid + t*256;
    const float4 w = *(const float4*)(cw + (size_t)o*4096 + (size_t)i*4);
    acc += (w.x + w.y + w.z + w.w) * in_b[i];
  }
  for (int off = 32; off; off >>= 1) acc += __shfl_down(acc, off);
  __shared__ float ls[4];
  if ((tid & 63) == 0) ls[tid >> 6] = acc;
  __syncthreads();
  if (tid == 0) cb2[o] = conv_b[o] + ls[0] + ls[1] + ls[2] + ls[3];
}

// ---------------- MFMA GEMM: C[m,n] = epi( sum_k A[m,k]*B[n,k] + bias[n] ) -------------
#define TBK 64

template<int EPI, int CONV, int NFRAG>
__launch_bounds__(256)
__global__ void mfma_gemm(const bf16* __restrict__ A, int lda,
                          const bf16* __restrict__ B, int ldb,
                          const float* __restrict__ bias,
                          float* __restrict__ outF,
                          bf16* __restrict__ outB0,
                          int ldo, int K, int azs, int ozs, int kzs)
{
  __shared__ bf16 As[128*TBK];           // 16 KB
  __shared__ bf16 Bs[32*NFRAG*TBK];      // 4/8 KB
  const int tid  = threadIdx.x;
  const int lane = tid & 63;
  const int wave = tid >> 6;
  const int wr = (wave >> 1) * 64;
  const int wc = (wave & 1) * 16 * NFRAG;
  const int mBase = blockIdx.x * 128;
  const int nBase = blockIdx.y * (32*NFRAG);
  A += (size_t)blockIdx.z * azs;
  const int nOff = blockIdx.z * ozs;
  const int koff = blockIdx.z * kzs;

  f32x4 acc[4][NFRAG] = {};

  for (int k0 = 0; k0 < K; k0 += TBK) {
    __syncthreads();
    #pragma unroll
    for (int it = 0; it < 4; it++) {      // As: 1024 chunks of 16B
      const int idx = it*256 + tid;
      const int r = idx >> 3, c16 = idx & 7;
      const bf16* ga;
      if (CONV) {
        const int tap = k0 >> 9, kk = k0 & 511;
        const int m = mBase + r;
        const int cc = m >> 8;
        int p = (m & 255) + tap - 2;
        p = min(max(p, 0), PP-1);
        ga = A + ((size_t)(cc*PP + p))*DMH + kk + c16*8;
      } else {
        ga = A + (size_t)(mBase + r)*lda + koff + k0 + c16*8;
      }
      g2l16(ga, &As[(size_t)idx*8]);
    }
    #pragma unroll
    for (int it = 0; it < NFRAG; it++) {  // Bs: 256*NFRAG chunks of 16B
      const int idx = it*256 + tid;
      const int r = idx >> 3, c16 = idx & 7;
      const bf16* gb = B + (size_t)(nBase + r)*ldb + koff + k0 + c16*8;
      g2l16(gb, &Bs[(size_t)idx*8]);
    }
    __syncthreads();
    #pragma unroll
    for (int ks = 0; ks < 2; ks++) {
      bf16x8 af[4], bfr[NFRAG];
      #pragma unroll
      for (int r = 0; r < 4; r++)
        af[r] = *(const bf16x8*)&As[(wr + r*16 + (lane & 15))*TBK + ks*32 + (lane>>4)*8];
      #pragma unroll
      for (int c = 0; c < NFRAG; c++)
        bfr[c] = *(const bf16x8*)&Bs[(wc + c*16 + (lane & 15))*TBK + ks*32 + (lane>>4)*8];
      #pragma unroll
      for (int r = 0; r < 4; r++)
        #pragma unroll
        for (int c = 0; c < NFRAG; c++)
          acc[r][c] = __builtin_amdgcn_mfma_f32_16x16x32_bf16(af[r], bfr[c], acc[r][c], 0, 0, 0);
    }
  }

  const int col0 = lane & 15;
  const int row0 = (lane >> 4) * 4;
  #pragma unroll
  for (int r = 0; r < 4; r++) {
    #pragma unroll
    for (int c = 0; c < NFRAG; c++) {
      #pragma unroll
      for (int reg = 0; reg < 4; reg++) {
        const int m = mBase + wr + r*16 + row0 + reg;
        const int n = nBase + wc + c*16 + col0;
        const float av = acc[r][c][reg];
        if (EPI == 0) {
          outF[(size_t)m*ldo + n] = av + bias[n];
        } else if (EPI == 1) {
          outB0[(size_t)m*ldo + n] = f2b(geluf(av + bias[n]));
        } else if (EPI == 2) {
          outB0[(size_t)m*ldo + n] = f2b(geluf(geluf(av + bias[n])));
        } else if (EPI == 3) {
          outB0[(size_t)m*ldo + n + nOff] = f2b(av);
        } else {
          const float vv = av + ((blockIdx.z == 0) ? bias[n] : 0.0f);
          atomicAdd(&outF[(size_t)m*ldo + n], vv);
        }
      }
    }
  }
}

// ---------------- chunked selective scan ----------------
// scan_a: dt GEMM tile (stored to dtg plane + LDS), 16-step chunk from s=0,
//         Ap = exp2(a2*sum dt).
// scan_b: per (c,d,n) 16-step serial prefix over chunk summaries -> sIn.
// scan_c: stages dtg (no recompute), replay from sIn, y/gz/D in writer phase.
__launch_bounds__(256)
__global__ void scan_a(const float* __restrict__ xdb, const bf16* __restrict__ xi,
                       const float* __restrict__ dt_w, const float* __restrict__ dt_b,
                       const float* __restrict__ A_log, float2* __restrict__ AS,
                       float* __restrict__ dtg)
{
  const int g = blockIdx.x, dg = blockIdx.y, c = blockIdx.z;
  const int tid = threadIdx.x;
  const int n = tid & 15, dl = tid >> 4;
  const int d0 = dg*16;
  const int d = d0 + dl;
  const int m0 = c*PP + g*16;
  __shared__ float  xdbT[16][68];   // +4 pad
  __shared__ float  dtw[16][33];    // +1 pad
  __shared__ float2 pxT[16][16];    // {dt, xi}
  {
    const int r = tid >> 4, c4 = (tid & 15)*4;
    *(float4*)&xdbT[r][c4] = *(const float4*)&xdb[(size_t)(m0 + r)*64 + c4];
    if (tid < 128){
      const int rr = tid >> 3, cc = (tid & 7)*4;
      *(float4*)&dtw[rr][cc] = *(const float4*)&dt_w[(size_t)(d0 + rr)*NDT + cc];
    }
    ushort u = ((const ushort*)xi)[(size_t)(m0 + r)*DIH + d0 + (tid & 15)];
    bf16 h; *(ushort*)&h = u;
    pxT[r][tid & 15].y = b2f(h);
  }
  const float a2 = -__expf(A_log[(size_t)d*NST + n]) * LOG2E;
  __syncthreads();
  {
    const int j = tid >> 4, dl2 = tid & 15;
    float acc = dt_b[d0 + dl2];
    #pragma unroll
    for (int k = 0; k < 32; k++) acc += xdbT[j][k] * dtw[dl2][k];
    acc = softplusf(acc);
    pxT[j][dl2].x = acc;
    dtg[(size_t)(m0 + j)*DIH + d0 + dl2] = acc;
  }
  __syncthreads();
  float Bv[16];
  #pragma unroll
  for (int j = 0; j < 16; j++) Bv[j] = xdbT[j][32 + n];
  float s = 0.f, dtsum = 0.f;
  #pragma unroll
  for (int j = 0; j < 16; j++){
    const float2 px = pxT[j][dl];
    const float e = exp2f(px.x * a2);
    s = s*e + (px.x * px.y) * Bv[j];
    dtsum += px.x;
  }
  float2 o; o.x = exp2f(dtsum * a2); o.y = s;
  AS[(((size_t)(c*64+dg))*16 + g)*256 + tid] = o;
}

__launch_bounds__(256)
__global__ void scan_b(const float2* __restrict__ AS, const float* __restrict__ s0,
                       float* __restrict__ sIn)
{
  const int dg = blockIdx.x, c = blockIdx.y;
  const int tid = threadIdx.x;
  const int n = tid & 15, dl = tid >> 4;
  const int d = dg*16 + dl;
  float s = s0[((size_t)c*DIH + d)*NST + n];
  const size_t base = (((size_t)(c*64+dg))*16)*256 + tid;
  float2 f[16];
  #pragma unroll
  for (int g = 0; g < 16; g++) f[g] = AS[base + g*256];
  #pragma unroll
  for (int g = 0; g < 16; g++){
    sIn[base + g*256] = s;
    s = f[g].y + f[g].x*s;
  }
}

__launch_bounds__(256)
__global__ void scan_c(const float* __restrict__ xdb, const bf16* __restrict__ xi,
                       const bf16* __restrict__ gz, const float* __restrict__ dtg,
                       const float* __restrict__ A_log, const float* __restrict__ Dp,
                       const float* __restrict__ sIn,
                       bf16* __restrict__ ypre, float* __restrict__ state_out)
{
  const int g = blockIdx.x, dg = blockIdx.y, c = blockIdx.z;
  const int tid = threadIdx.x;
  const int n = tid & 15, dl = tid >> 4;
  const int d0 = dg*16;
  const int d = d0 + dl;
  const int m0 = c*PP + g*16;
  __shared__ float  bcT[16][34];    // B|C cols 32..63, +2 pad
  __shared__ float2 pxT[16][16];    // {dt, xi}
  __shared__ ushort gzT[16][16];
  __shared__ float  ybF[16][16];
  __shared__ float  DvT[16];
  {
    const int r = tid >> 4, cc = (tid & 15)*2;
    *(float2*)&bcT[r][cc] = *(const float2*)&xdb[(size_t)(m0 + r)*64 + 32 + cc];
    const int dd = tid & 15;
    float2 px;
    px.x = dtg[(size_t)(m0 + r)*DIH + d0 + dd];
    ushort u = ((const ushort*)xi)[(size_t)(m0 + r)*DIH + d0 + dd];
    bf16 h; *(ushort*)&h = u;
    px.y = b2f(h);
    pxT[r][dd] = px;
    gzT[r][dd] = ((const ushort*)gz)[(size_t)(m0 + r)*DIH + d0 + dd];
    if (tid < 16) DvT[tid] = Dp[d0 + tid];
  }
  const float a2 = -__expf(A_log[(size_t)d*NST + n]) * LOG2E;
  float s = sIn[(((size_t)(c*64+dg))*16 + g)*256 + tid];
  __syncthreads();
  float Bv[16], Cv[16];
  #pragma unroll
  for (int j = 0; j < 16; j++){ Bv[j] = bcT[j][n]; Cv[j] = bcT[j][16 + n]; }
  #pragma unroll
  for (int j = 0; j < 16; j++){
    const float2 px = pxT[j][dl];
    const float e = exp2f(px.x * a2);
    s = s*e + (px.x * px.y) * Bv[j];
    const float y = row_sum16(s * Cv[j]);   // valid at n==15
    if (n == 15) ybF[j][dl] = y;
  }
  __syncthreads();
  if (tid < 32){
    const int j = tid >> 1, half = (tid & 1)*8;
    ushort o[8];
    #pragma unroll
    for (int t = 0; t < 8; t++){
      const int dd = half + t;
      bf16 gh; *(ushort*)&gh = gzT[j][dd];
      bf16 h = f2b((ybF[j][dd] + DvT[dd]*pxT[j][dd].y) * b2f(gh));
      o[t] = *(const ushort*)&h;
    }
    *(uint4*)((ushort*)ypre + (size_t)(m0 + j)*DIH + d0 + half) = *(const uint4*)o;
  }
  if (g == 15) state_out[((size_t)c*DIH + d)*NST + n] = s;
}

extern "C" void kernel_launch(void* const* d_in, const int* in_sizes, int n_in,
                              void* d_out, int out_size, void* d_ws, size_t ws_size,
                              hipStream_t stream) {
  const float* x       = (const float*)d_in[0];
  const float* s0      = (const float*)d_in[1];
  const float* in_w    = (const float*)d_in[2];
  const float* in_b    = (const float*)d_in[3];
  const float* conv_w  = (const float*)d_in[4];
  const float* conv_b  = (const float*)d_in[5];
  const float* param_w = (const float*)d_in[6];
  const float* param_b = (const float*)d_in[7];
  const float* dt_w    = (const float*)d_in[8];
  const float* dt_b    = (const float*)d_in[9];
  const float* out_w   = (const float*)d_in[10];
  const float* out_b   = (const float*)d_in[11];
  const float* A_log   = (const float*)d_in[12];
  const float* Dp      = (const float*)d_in[13];

  char* ws = (char*)d_ws;
  bf16*   xi    = (bf16*)ws;   ws += (size_t)MM*DIH*2;     //  8 MB
  bf16*   gz    = (bf16*)ws;   ws += (size_t)MM*DIH*2;     //  8 MB
  float*  xdb   = (float*)ws;  ws += (size_t)MM*64*4;      //  1 MB
  float*  cb2   = (float*)ws;  ws += 4096;                 //  4 KB
  bf16*   ypre  = (bf16*)ws;   ws += (size_t)MM*DIH*2;     //  8 MB
  bf16*   outwb = (bf16*)ws;   ws += (size_t)DMH*DIH*2;    //  1 MB
  bf16*   pwb   = (bf16*)ws;   ws += (size_t)64*DIH*2;     // 128 KB
  float*  dtg   = (float*)ws;  ws += (size_t)MM*DIH*4;     // 16 MB (scan_a -> scan_c)
  float*  sIn   = (float*)ws;  ws += (size_t)MM*NST*4;     // 16 MB (scan_b -> scan_c)
  char*   U     = ws;          ws += (size_t)32*1024*1024; // union region, 32 MB
  // early-phase tenants of U (all dead before scan_a):
  bf16* Wfb  = (bf16*)(U);
  bf16* xbf  = (bf16*)(U + (size_t) 4*1024*1024);
  bf16* inwz = (bf16*)(U + (size_t) 8*1024*1024);
  bf16* inwT = (bf16*)(U + (size_t) 9*1024*1024);
  bf16* cwT  = (bf16*)(U + (size_t)10*1024*1024);
  // scan-phase tenant of U:
  float2* AS  = (float2*)(U);                              // 32 MB

  float* y_out  = (float*)d_out;                           // [C,P,DM] fp32
  float* st_out = y_out + (size_t)MM*DMH;                  // [C,DI,16] fp32

  // fused prep (casts, conv repack, tiled transpose, xdb zero) + fold_bias
  prep_all<<<7616, 256, 0, stream>>>(x, in_w, out_w, param_w, conv_w,
                                     xbf, inwz, outwb, pwb, cwT, inwT, (float4*)xdb);
  fold_bias<<<DIH, 256, 0, stream>>>(conv_w, in_b, conv_b, cb2);

  // fold: Wf[k][o][m] = sum_i conv_w[o,i,k]*in_w[i,m]   (4 taps via grid.z)
  mfma_gemm<3,0,2><<<dim3(DIH/128, DMH/64, 4), 256, 0, stream>>>(
      cwT, DIH, inwT, DIH, nullptr, nullptr, Wfb, 4*DMH, DIH, DIH*DIH, DMH, 0);
  // z-half in_proj: gelu(gelu(x @ in_w_z^T + b_z)) -> gz (contiguous bf16)
  mfma_gemm<2,0,2><<<dim3(MM/128, DIH/64), 256, 0, stream>>>(
      xbf, DMH, inwz, DMH, in_b + DIH, nullptr, gz, DIH, DMH, 0, 0, 0);
  // fused conv: gelu( sum_tap x[clamp] @ Wf_tap^T + cb2 ) -> xi (contiguous bf16)
  mfma_gemm<1,1,2><<<dim3(MM/128, DIH/64), 256, 0, stream>>>(
      xbf, DMH, Wfb, 4*DMH, cb2, nullptr, xi, DIH, 4*DMH, 0, 0, 0);
  // x_db = xi @ param_w.T + param_b   (MFMA split-K=8, fp32 atomics into zeroed xdb)
  mfma_gemm<4,0,2><<<dim3(MM/128, 1, 8), 256, 0, stream>>>(
      xi, DIH, pwb, DIH, param_b, xdb, nullptr, 64, 128, 0, 0, 128);
  // chunked scan: A (dt GEMM + chunk-from-0) -> B (prefix) -> C (replay)
  scan_a<<<dim3(16, 64, CC), 256, 0, stream>>>(xdb, xi, dt_w, dt_b, A_log, AS, dtg);
  scan_b<<<dim3(64, CC), 256, 0, stream>>>(AS, s0, sIn);
  scan_c<<<dim3(16, 64, CC), 256, 0, stream>>>(xdb, xi, gz, dtg, A_log, Dp, sIn,
                                               ypre, st_out);
  // out projection
  mfma_gemm<0,0,1><<<dim3(MM/128, DMH/32), 256, 0, stream>>>(
      ypre, DIH, outwb, DIH, out_b, y_out, nullptr, DMH, DIH, 0, 0, 0);
}